// Round 1
// 63.273 us; speedup vs baseline: 1.0312x; 1.0312x over previous
//
#include <hip/hip_runtime.h>

#define NPTS 2048

__global__ __launch_bounds__(256, 4) void spring_kernel(
    const float* __restrict__ X,
    const float* __restrict__ Kp,
    const float* __restrict__ Bp,
    float* __restrict__ out)
{
    __shared__ __align__(16) float xs[NPTS];
    __shared__ __align__(16) float ys[NPTS];
    __shared__ __align__(16) float zs[NPTS];

    const int tid    = threadIdx.x;
    const int b      = blockIdx.x >> 8;            // 256 blocks per batch
    const int i_base = (blockIdx.x & 255) << 3;    // 8 i's per block
    const float* Xb  = X + b * (NPTS * 3);

    const float K  = Kp[0];
    const float KB = K * Bp[0];

    // ---- Stage batch coords into LDS as SoA via float4 loads ----
    // Thread g handles points 4g..4g+3 (3 float4s = 12 floats), deinterleaves
    // in registers, writes 3 conflict-free ds_write_b128. No div/mod, no branches.
    {
        const float4* Xb4 = (const float4*)Xb;
        float4* xs4w = (float4*)xs;
        float4* ys4w = (float4*)ys;
        float4* zs4w = (float4*)zs;
        #pragma unroll
        for (int g0 = 0; g0 < NPTS / 4; g0 += 256) {
            const int g = g0 + tid;
            float4 f0 = Xb4[3 * g + 0];   // x0 y0 z0 x1
            float4 f1 = Xb4[3 * g + 1];   // y1 z1 x2 y2
            float4 f2 = Xb4[3 * g + 2];   // z2 x3 y3 z3
            xs4w[g] = make_float4(f0.x, f0.w, f1.z, f2.y);
            ys4w[g] = make_float4(f0.y, f1.x, f1.w, f2.z);
            zs4w[g] = make_float4(f0.z, f1.y, f2.x, f2.w);
        }
    }
    __syncthreads();

    // One wave per 2 i's; all 64 lanes slice the j-range.
    const int wv   = tid >> 6;          // 0..3
    const int lane = tid & 63;
    const int i0   = i_base + wv * 2;

    const float xi0 = xs[i0],     yi0 = ys[i0],     zi0 = zs[i0];
    const float xi1 = xs[i0 + 1], yi1 = ys[i0 + 1], zi1 = zs[i0 + 1];

    float ax0 = 0.f, ay0 = 0.f, az0 = 0.f;
    float ax1 = 0.f, ay1 = 0.f, az1 = 0.f;

    const float4* xs4 = (const float4*)xs;
    const float4* ys4 = (const float4*)ys;
    const float4* zs4 = (const float4*)zs;

    // 512 float4s / 64 lanes = 8 iters; each iter: 3 ds_read_b128 -> 8 pairs
    #pragma unroll 4
    for (int t = 0; t < NPTS / 4 / 64; ++t) {
        const int idx = (t << 6) + lane;
        float4 jx = xs4[idx];
        float4 jy = ys4[idx];
        float4 jz = zs4[idx];
        const float jxa[4] = {jx.x, jx.y, jx.z, jx.w};
        const float jya[4] = {jy.x, jy.y, jy.z, jy.w};
        const float jza[4] = {jz.x, jz.y, jz.z, jz.w};

        #pragma unroll
        for (int c = 0; c < 4; ++c) {
            // i0
            {
                float dx = xi0 - jxa[c];
                float dy = yi0 - jya[c];
                float dz = zi0 - jza[c];
                // fold the diagonal clamp into the fma chain (saves fmax):
                float sq = fmaf(dx, dx, fmaf(dy, dy, fmaf(dz, dz, 1e-30f)));
                float r  = __builtin_amdgcn_rsqf(sq);
                float s  = fmaf(-KB, r, K);          // K*(d-B)/d
                ax0 = fmaf(dx, s, ax0);
                ay0 = fmaf(dy, s, ay0);
                az0 = fmaf(dz, s, az0);
            }
            // i0+1
            {
                float dx = xi1 - jxa[c];
                float dy = yi1 - jya[c];
                float dz = zi1 - jza[c];
                float sq = fmaf(dx, dx, fmaf(dy, dy, fmaf(dz, dz, 1e-30f)));
                float r  = __builtin_amdgcn_rsqf(sq);
                float s  = fmaf(-KB, r, K);
                ax1 = fmaf(dx, s, ax1);
                ay1 = fmaf(dy, s, ay1);
                az1 = fmaf(dz, s, az1);
            }
        }
    }

    // Full-wave reduction (64 lanes) for both i's (6 independent chains)
    #pragma unroll
    for (int d = 32; d > 0; d >>= 1) {
        ax0 += __shfl_down(ax0, d, 64);
        ay0 += __shfl_down(ay0, d, 64);
        az0 += __shfl_down(az0, d, 64);
        ax1 += __shfl_down(ax1, d, 64);
        ay1 += __shfl_down(ay1, d, 64);
        az1 += __shfl_down(az1, d, 64);
    }

    if (lane == 0) {
        float* o = out + (b * NPTS + i0) * 3;   // 6 consecutive floats
        o[0] = xi0 + ax0;
        o[1] = yi0 + ay0;
        o[2] = zi0 + az0;
        o[3] = xi1 + ax1;
        o[4] = yi1 + ay1;
        o[5] = zi1 + az1;
    }
}

extern "C" void kernel_launch(void* const* d_in, const int* in_sizes, int n_in,
                              void* d_out, int out_size, void* d_ws, size_t ws_size,
                              hipStream_t stream) {
    const float* X  = (const float*)d_in[0];
    const float* Kp = (const float*)d_in[1];
    const float* Bp = (const float*)d_in[2];
    float* out = (float*)d_out;

    dim3 grid(4 * (NPTS / 8));   // 1024 blocks, 8 i's each
    dim3 block(256);
    spring_kernel<<<grid, block, 0, stream>>>(X, Kp, Bp, out);
}

// Round 2
// 63.086 us; speedup vs baseline: 1.0343x; 1.0030x over previous
//
#include <hip/hip_runtime.h>

#define NPTS 2048

__global__ __launch_bounds__(512, 8) void spring_kernel(
    const float* __restrict__ X,
    const float* __restrict__ Kp,
    const float* __restrict__ Bp,
    float* __restrict__ out)
{
    __shared__ __align__(16) float xs[NPTS];
    __shared__ __align__(16) float ys[NPTS];
    __shared__ __align__(16) float zs[NPTS];

    const int tid    = threadIdx.x;
    const int b      = blockIdx.x >> 8;            // 256 blocks per batch
    const int i_base = (blockIdx.x & 255) << 3;    // 8 i's per block
    const float* Xb  = X + b * (NPTS * 3);

    const float K  = Kp[0];
    const float KB = K * Bp[0];

    // ---- Stage batch coords into LDS as SoA via float4 loads ----
    // 512 threads, 512 four-point groups: exactly one branch-free iteration.
    // Thread g handles points 4g..4g+3 (3 float4s), deinterleaves in registers,
    // writes 3 conflict-free ds_write_b128.
    {
        const float4* Xb4 = (const float4*)Xb;
        float4* xs4w = (float4*)xs;
        float4* ys4w = (float4*)ys;
        float4* zs4w = (float4*)zs;
        const int g = tid;
        float4 f0 = Xb4[3 * g + 0];   // x0 y0 z0 x1
        float4 f1 = Xb4[3 * g + 1];   // y1 z1 x2 y2
        float4 f2 = Xb4[3 * g + 2];   // z2 x3 y3 z3
        xs4w[g] = make_float4(f0.x, f0.w, f1.z, f2.y);
        ys4w[g] = make_float4(f0.y, f1.x, f1.w, f2.z);
        zs4w[g] = make_float4(f0.z, f1.y, f2.x, f2.w);
    }
    __syncthreads();

    // 8 waves per block, ONE i per wave; all 64 lanes slice the j-range.
    // 32 waves/CU (hardware max) at 4 blocks/CU; VGPR budget 64.
    const int wv   = tid >> 6;          // 0..7
    const int lane = tid & 63;
    const int i    = i_base + wv;

    const float xi = xs[i], yi = ys[i], zi = zs[i];

    float ax = 0.f, ay = 0.f, az = 0.f;

    const float4* xs4 = (const float4*)xs;
    const float4* ys4 = (const float4*)ys;
    const float4* zs4 = (const float4*)zs;

    // 512 float4s / 64 lanes = 8 iters; each iter: 3 ds_read_b128 -> 4 pairs
    #pragma unroll 2
    for (int t = 0; t < NPTS / 4 / 64; ++t) {
        const int idx = (t << 6) + lane;
        float4 jx = xs4[idx];
        float4 jy = ys4[idx];
        float4 jz = zs4[idx];
        const float jxa[4] = {jx.x, jx.y, jx.z, jx.w};
        const float jya[4] = {jy.x, jy.y, jy.z, jy.w};
        const float jza[4] = {jz.x, jz.y, jz.z, jz.w};

        #pragma unroll
        for (int c = 0; c < 4; ++c) {
            float dx = xi - jxa[c];
            float dy = yi - jya[c];
            float dz = zi - jza[c];
            // fold the diagonal clamp into the fma chain (saves fmax):
            float sq = fmaf(dx, dx, fmaf(dy, dy, fmaf(dz, dz, 1e-30f)));
            float r  = __builtin_amdgcn_rsqf(sq);
            float s  = fmaf(-KB, r, K);          // K*(d-B)/d
            ax = fmaf(dx, s, ax);
            ay = fmaf(dy, s, ay);
            az = fmaf(dz, s, az);
        }
    }

    // Full-wave reduction (64 lanes), 3 independent chains
    #pragma unroll
    for (int d = 32; d > 0; d >>= 1) {
        ax += __shfl_down(ax, d, 64);
        ay += __shfl_down(ay, d, 64);
        az += __shfl_down(az, d, 64);
    }

    if (lane == 0) {
        float* o = out + (b * NPTS + i) * 3;
        o[0] = xi + ax;
        o[1] = yi + ay;
        o[2] = zi + az;
    }
}

extern "C" void kernel_launch(void* const* d_in, const int* in_sizes, int n_in,
                              void* d_out, int out_size, void* d_ws, size_t ws_size,
                              hipStream_t stream) {
    const float* X  = (const float*)d_in[0];
    const float* Kp = (const float*)d_in[1];
    const float* Bp = (const float*)d_in[2];
    float* out = (float*)d_out;

    dim3 grid(4 * (NPTS / 8));   // 1024 blocks, 8 i's each
    dim3 block(512);             // 8 waves, 1 i per wave -> 32 waves/CU
    spring_kernel<<<grid, block, 0, stream>>>(X, Kp, Bp, out);
}